// Round 2
// baseline (140.499 us; speedup 1.0000x reference)
//
#include <hip/hip_runtime.h>
#include <math.h>

#define BT    34   // sequence length
#define TPR   17   // j index range: thread owns tokens j and j+17
#define RPB   15   // rows per block (15*17 = 255 active threads of 256)
#define BLOCK 256

typedef float v2f __attribute__((ext_vector_type(2)));
typedef float v4f __attribute__((ext_vector_type(4)));

// log2(e)/sqrt(3): folds the 1/sqrt(hd) scale AND the exp->exp2 conversion into q.
#define QSCALE 0.83294037332470f

#if __has_builtin(__builtin_amdgcn_exp2f)
#define EXP2(x) __builtin_amdgcn_exp2f(x)
#else
#define EXP2(x) exp2f(x)
#endif

// token-packed normalize-only layernorm (affine folded into downstream weights)
__device__ __forceinline__ void ln6n(const v2f* x, v2f* o) {
  v2f mu = (x[0]+x[1]+x[2]+x[3]+x[4]+x[5]) * (1.0f/6.0f);
  v2f v = (v2f){0.f, 0.f};
  #pragma unroll
  for (int c = 0; c < 6; ++c) { v2f d = x[c]-mu; v += d*d; }
  v2f inv = (v2f){ rsqrtf(v.x*(1.0f/6.0f) + 1e-5f),
                   rsqrtf(v.y*(1.0f/6.0f) + 1e-5f) };
  #pragma unroll
  for (int c = 0; c < 6; ++c) o[c] = (x[c]-mu)*inv;
}

__global__ __launch_bounds__(BLOCK, 6)
void addtrans_kernel(const int* __restrict__ idx,
                     const float* __restrict__ tok_emb,
                     const float* __restrict__ pos_params,
                     const float* __restrict__ z10_enc,
                     const float* __restrict__ special_enc,
                     const float* __restrict__ wq,
                     const float* __restrict__ wk,
                     const float* __restrict__ wv,
                     const float* __restrict__ wo,
                     const float* __restrict__ ln1_g, const float* __restrict__ ln1_b,
                     const float* __restrict__ ln2_g, const float* __restrict__ ln2_b,
                     const float* __restrict__ lnf_g, const float* __restrict__ lnf_b,
                     const float* __restrict__ ffn_w1, const float* __restrict__ ffn_b1,
                     const float* __restrict__ ffn_w2, const float* __restrict__ ffn_b2,
                     const float* __restrict__ head_w,
                     float* __restrict__ out, int B)
{
  // kv only: [t][row][12] = 6120 floats (+180 pad so the rolling prefetch's
  // dead last read at index <=6299 stays inside the array)
  __shared__ __align__(16) float s_mem[RPB*BT*12 + 180];
  __shared__ float s_te[42];
  __shared__ float s_pos[BT*3];
  __shared__ float s_wqf[18], s_wkf[18], s_wvf[18];   // ln1_g folded in
  __shared__ float s_qb[6], s_kb[6], s_vb[6];         // ln1_b folded in
  __shared__ float s_wo[36];
  __shared__ float s_w1f[12], s_fb1f[2];              // ln2_g/ln2_b folded in
  __shared__ float s_w2[12], s_fb2[6];
  __shared__ float s_hwf[18], s_yb[3];                // lnf_g/lnf_b folded in

  const int tid = threadIdx.x;
  const int b0  = blockIdx.x * RPB;

  // ---- stage params with LN-affine folds (all reads from GLOBAL: no ordering dep) ----
  if (tid < 42) s_te[tid] = tok_emb[tid];
  if (tid < 18) {
    const int r = tid / 6;
    s_wqf[tid] = wq[tid] * ln1_g[3+r];
    s_wkf[tid] = wk[tid] * ln1_g[3+r];
    s_wvf[tid] = wv[tid] * ln1_g[r];
    s_hwf[tid] = head_w[tid] * lnf_g[tid/3];
  }
  if (tid < 36) s_wo[tid] = wo[tid];
  if (tid < 12) { s_w1f[tid] = ffn_w1[tid] * ln2_g[tid>>1]; s_w2[tid] = ffn_w2[tid]; }
  if (tid < 6)  {
    s_qb[tid] = ln1_b[3]*wq[tid] + ln1_b[4]*wq[6+tid] + ln1_b[5]*wq[12+tid];
    s_kb[tid] = ln1_b[3]*wk[tid] + ln1_b[4]*wk[6+tid] + ln1_b[5]*wk[12+tid];
    s_vb[tid] = ln1_b[0]*wv[tid] + ln1_b[1]*wv[6+tid] + ln1_b[2]*wv[12+tid];
    s_fb2[tid] = ffn_b2[tid];
  }
  if (tid < 3) {
    float a = 0.f;
    #pragma unroll
    for (int c = 0; c < 6; ++c) a += lnf_b[c]*head_w[c*3+tid];
    s_yb[tid] = a;
  }
  if (tid < 2) {
    float a = ffn_b1[tid];
    #pragma unroll
    for (int d = 0; d < 6; ++d) a += ln2_b[d]*ffn_w1[d*2+tid];
    s_fb1f[tid] = a;
  }
  if (tid < BT) {
    int p = tid, f;
    if (p < 10) f = p;
    else if (p == 10) f = 11;
    else if (p < 21) f = p - 11;
    else if (p == 21) f = 12;
    else if (p < 33) { int z = p - 22; f = (z < 10) ? z : 10; }
    else f = 13;
    float e0, e1, e2;
    if (f < 10) {
      float amp = pos_params[0], ph = pos_params[1], sl = pos_params[2], of = pos_params[3];
      float ang = 0.62831853071795864769f * (float)f + ph;  // 2*pi*f/10 + phase
      e0 = amp * cosf(ang); e1 = amp * sinf(ang); e2 = sl * (float)f + of;
    } else if (f == 10) { e0 = z10_enc[0]; e1 = z10_enc[1]; e2 = z10_enc[2]; }
    else { int u = f - 11; e0 = special_enc[u*3]; e1 = special_enc[u*3+1]; e2 = special_enc[u*3+2]; }
    s_pos[tid*3+0] = e0; s_pos[tid*3+1] = e1; s_pos[tid*3+2] = e2;
  }
  __syncthreads();

  // transposed layout: waves hold a narrow j-band so causal trip counts are near-uniform
  const int row = tid % RPB;           // 0..14
  const int j   = tid / RPB;           // 0..16 (17 => inactive lane 255)
  const int b   = b0 + row;
  const bool active = (j < TPR) && (b < B);

  v2f qpA[3], qpB[3];                  // per-token q, packed over heads, scaled by QSCALE
  v2f x6[6];                           // residual x, packed over tokens (A,B)

  // ---- embed + ln1(folded) + qkv, token-packed; publish k,v to LDS [t][row] ----
  if (active) {
    const int tA = j, tB = j + TPR;
    const int vA = idx[b*BT + tA];     // block's idx region is ~2KB: L1-resident
    const int vB = idx[b*BT + tB];
    #pragma unroll
    for (int c = 0; c < 3; ++c) {
      x6[c]   = (v2f){ s_te[vA*3+c],  s_te[vB*3+c]  };
      x6[3+c] = (v2f){ s_pos[tA*3+c], s_pos[tB*3+c] };
    }
    v2f h[6];
    ln6n(x6, h);
    v2f q6[6], k6[6], v6[6];
    #pragma unroll
    for (int c = 0; c < 6; ++c) {
      q6[c] = (v2f){s_qb[c], s_qb[c]} + h[3]*s_wqf[c] + h[4]*s_wqf[6+c] + h[5]*s_wqf[12+c];
      k6[c] = (v2f){s_kb[c], s_kb[c]} + h[3]*s_wkf[c] + h[4]*s_wkf[6+c] + h[5]*s_wkf[12+c];
      v6[c] = (v2f){s_vb[c], s_vb[c]} + h[0]*s_wvf[c] + h[1]*s_wvf[6+c] + h[2]*s_wvf[12+c];
    }
    #pragma unroll
    for (int d = 0; d < 3; ++d) {
      qpA[d] = (v2f){ q6[d].x, q6[3+d].x } * QSCALE;
      qpB[d] = (v2f){ q6[d].y, q6[3+d].y } * QSCALE;
    }
    v4f* pA = (v4f*)&s_mem[(tA*RPB + row)*12];
    pA[0] = (v4f){ k6[0].x, k6[3].x, k6[1].x, k6[4].x };
    pA[1] = (v4f){ k6[2].x, k6[5].x, v6[0].x, v6[3].x };
    pA[2] = (v4f){ v6[1].x, v6[4].x, v6[2].x, v6[5].x };
    v4f* pB = (v4f*)&s_mem[(tB*RPB + row)*12];
    pB[0] = (v4f){ k6[0].y, k6[3].y, k6[1].y, k6[4].y };
    pB[1] = (v4f){ k6[2].y, k6[5].y, v6[0].y, v6[3].y };
    pB[2] = (v4f){ v6[1].y, v6[4].y, v6[2].y, v6[5].y };
  }
  __syncthreads();

  // ---- causal attention: trip count IS the mask; rolling 1-deep kv prefetch ----
  v2f l0 = (v2f){0.f,0.f}, l1 = (v2f){0.f,0.f};
  v2f o0[3] = {(v2f){0.f,0.f},(v2f){0.f,0.f},(v2f){0.f,0.f}};
  v2f o1[3] = {(v2f){0.f,0.f},(v2f){0.f,0.f},(v2f){0.f,0.f}};
  if (active) {
    const float* kvbase = s_mem + row*12;
    v4f A  = ((const v4f*)kvbase)[0];
    v4f Bv = ((const v4f*)kvbase)[1];
    v4f C  = ((const v4f*)kvbase)[2];
    // k = 0..j : both tokens, no mask (wave runs jmax+1 iters: 5/9/13/17 per wave)
    for (int k = 0; k <= j; ++k) {
      const v4f Ac = A, Bc = Bv, Cc = C;
      const v4f* nxt = (const v4f*)(kvbase + (k+1)*(RPB*12));   // k+1<=17, in bounds
      A = nxt[0]; Bv = nxt[1]; C = nxt[2];
      v2f kA = (v2f){Ac.x, Ac.y}, kB = (v2f){Ac.z, Ac.w}, kC = (v2f){Bc.x, Bc.y};
      v2f vA = (v2f){Bc.z, Bc.w}, vB = (v2f){Cc.x, Cc.y}, vC = (v2f){Cc.z, Cc.w};
      v2f s0 = qpA[0]*kA + qpA[1]*kB + qpA[2]*kC;
      v2f p0 = (v2f){EXP2(s0.x), EXP2(s0.y)};
      l0 += p0; o0[0] += p0*vA; o0[1] += p0*vB; o0[2] += p0*vC;
      v2f s1 = qpB[0]*kA + qpB[1]*kB + qpB[2]*kC;
      v2f p1 = (v2f){EXP2(s1.x), EXP2(s1.y)};
      l1 += p1; o1[0] += p1*vA; o1[1] += p1*vB; o1[2] += p1*vC;
    }
    // k = j+1..j+17 : token B only, exactly 17 iters for every lane (uniform trip).
    // A/Bv/C already hold kv[j+1] from the last prefetch above.
    #pragma unroll 4
    for (int i = 1; i <= TPR; ++i) {
      const int k = j + i;
      const v4f Ac = A, Bc = Bv, Cc = C;
      const v4f* nxt = (const v4f*)(kvbase + (k+1)*(RPB*12));   // max idx 6299: inside pad, value unused
      A = nxt[0]; Bv = nxt[1]; C = nxt[2];
      v2f kA = (v2f){Ac.x, Ac.y}, kB = (v2f){Ac.z, Ac.w}, kC = (v2f){Bc.x, Bc.y};
      v2f vA = (v2f){Bc.z, Bc.w}, vB = (v2f){Cc.x, Cc.y}, vC = (v2f){Cc.z, Cc.w};
      v2f s1 = qpB[0]*kA + qpB[1]*kB + qpB[2]*kC;
      v2f p1 = (v2f){EXP2(s1.x), EXP2(s1.y)};
      l1 += p1; o1[0] += p1*vA; o1[1] += p1*vB; o1[2] += p1*vC;
    }
  }
  // no further LDS use: no barrier needed

  // ---- epilogue, token-packed: o/l, wo, residual, ln2(folded), FFN(exact gelu),
  //      lnf(folded), head, logits -> DIRECT global stores (7x dwordx2 per token) ----
  if (active) {
    const float rA0 = __builtin_amdgcn_rcpf(l0.x);
    const float rA1 = __builtin_amdgcn_rcpf(l0.y);
    const float rB0 = __builtin_amdgcn_rcpf(l1.x);
    const float rB1 = __builtin_amdgcn_rcpf(l1.y);
    v2f a6[6];
    a6[0] = (v2f){ o0[0].x*rA0, o1[0].x*rB0 };
    a6[1] = (v2f){ o0[1].x*rA0, o1[1].x*rB0 };
    a6[2] = (v2f){ o0[2].x*rA0, o1[2].x*rB0 };
    a6[3] = (v2f){ o0[0].y*rA1, o1[0].y*rB1 };
    a6[4] = (v2f){ o0[1].y*rA1, o1[1].y*rB1 };
    a6[5] = (v2f){ o0[2].y*rA1, o1[2].y*rB1 };
    v2f xn[6];
    #pragma unroll
    for (int c = 0; c < 6; ++c) {
      xn[c] = x6[c]
            + a6[0]*s_wo[c]    + a6[1]*s_wo[6+c]  + a6[2]*s_wo[12+c]
            + a6[3]*s_wo[18+c] + a6[4]*s_wo[24+c] + a6[5]*s_wo[30+c];
    }
    v2f t2[6];
    ln6n(xn, t2);
    v2f a0 = (v2f){s_fb1f[0], s_fb1f[0]};
    v2f a1 = (v2f){s_fb1f[1], s_fb1f[1]};
    #pragma unroll
    for (int d = 0; d < 6; ++d) { a0 += t2[d]*s_w1f[d*2]; a1 += t2[d]*s_w1f[d*2+1]; }
    const float KIS2 = 0.70710678118654752440f;
    v2f g0 = (v2f){ 0.5f*a0.x*(1.0f + erff(a0.x*KIS2)),
                    0.5f*a0.y*(1.0f + erff(a0.y*KIS2)) };
    v2f g1 = (v2f){ 0.5f*a1.x*(1.0f + erff(a1.x*KIS2)),
                    0.5f*a1.y*(1.0f + erff(a1.y*KIS2)) };
    #pragma unroll
    for (int c = 0; c < 6; ++c) xn[c] += g0*s_w2[c] + g1*s_w2[6+c] + s_fb2[c];
    v2f tf[6];
    ln6n(xn, tf);
    v2f y0 = (v2f){s_yb[0], s_yb[0]};
    v2f y1 = (v2f){s_yb[1], s_yb[1]};
    v2f y2 = (v2f){s_yb[2], s_yb[2]};
    #pragma unroll
    for (int c = 0; c < 6; ++c) {
      y0 += tf[c]*s_hwf[c*3+0]; y1 += tf[c]*s_hwf[c*3+1]; y2 += tf[c]*s_hwf[c*3+2];
    }
    // logits, token-packed per channel; store each token's 14 floats as 7x v2f.
    // PLAIN stores (not nontemporal): partial-line writes must merge in L2.
    float* oA = out + ((size_t)b * BT + j) * 14;
    float* oB = oA + TPR * 14;
    #pragma unroll
    for (int u = 0; u < 7; ++u) {
      const int c0 = 2*u, c1 = 2*u+1;
      v2f lg0 = y0*s_te[c0*3+0] + y1*s_te[c0*3+1] + y2*s_te[c0*3+2];
      v2f lg1 = y0*s_te[c1*3+0] + y1*s_te[c1*3+1] + y2*s_te[c1*3+2];
      *reinterpret_cast<v2f*>(oA + 2*u) = (v2f){ lg0.x, lg1.x };
      *reinterpret_cast<v2f*>(oB + 2*u) = (v2f){ lg0.y, lg1.y };
    }
  }
}

extern "C" void kernel_launch(void* const* d_in, const int* in_sizes, int n_in,
                              void* d_out, int out_size, void* d_ws, size_t ws_size,
                              hipStream_t stream) {
  const int B = in_sizes[0] / BT;                 // 32768
  const int grid = (B + RPB - 1) / RPB;           // 2185
  addtrans_kernel<<<grid, BLOCK, 0, stream>>>(
      (const int*)d_in[0],   (const float*)d_in[1], (const float*)d_in[2],
      (const float*)d_in[3], (const float*)d_in[4], (const float*)d_in[5],
      (const float*)d_in[6], (const float*)d_in[7], (const float*)d_in[8],
      (const float*)d_in[9], (const float*)d_in[10], (const float*)d_in[11],
      (const float*)d_in[12], (const float*)d_in[13], (const float*)d_in[14],
      (const float*)d_in[15], (const float*)d_in[16], (const float*)d_in[17],
      (const float*)d_in[18], (const float*)d_in[19],
      (float*)d_out, B);
}

// Round 3
// 133.861 us; speedup vs baseline: 1.0496x; 1.0496x over previous
//
#include <hip/hip_runtime.h>
#include <math.h>

#define BT    34   // sequence length
#define TPR   17   // j index range: thread owns tokens j and j+17
#define RPB   15   // rows per block (15*17 = 255 active threads of 256)
#define BLOCK 256

typedef float v2f __attribute__((ext_vector_type(2)));
typedef float v4f __attribute__((ext_vector_type(4)));

// log2(e)/sqrt(3): folds the 1/sqrt(hd) scale AND the exp->exp2 conversion into q.
#define QSCALE 0.83294037332470f

#if __has_builtin(__builtin_amdgcn_exp2f)
#define EXP2(x) __builtin_amdgcn_exp2f(x)
#else
#define EXP2(x) exp2f(x)
#endif

// token-packed normalize-only layernorm (affine folded into downstream weights)
__device__ __forceinline__ void ln6n(const v2f* x, v2f* o) {
  v2f mu = (x[0]+x[1]+x[2]+x[3]+x[4]+x[5]) * (1.0f/6.0f);
  v2f v = (v2f){0.f, 0.f};
  #pragma unroll
  for (int c = 0; c < 6; ++c) { v2f d = x[c]-mu; v += d*d; }
  v2f inv = (v2f){ rsqrtf(v.x*(1.0f/6.0f) + 1e-5f),
                   rsqrtf(v.y*(1.0f/6.0f) + 1e-5f) };
  #pragma unroll
  for (int c = 0; c < 6; ++c) o[c] = (x[c]-mu)*inv;
}

__global__ __launch_bounds__(BLOCK, 5)
void addtrans_kernel(const int* __restrict__ idx,
                     const float* __restrict__ tok_emb,
                     const float* __restrict__ pos_params,
                     const float* __restrict__ z10_enc,
                     const float* __restrict__ special_enc,
                     const float* __restrict__ wq,
                     const float* __restrict__ wk,
                     const float* __restrict__ wv,
                     const float* __restrict__ wo,
                     const float* __restrict__ ln1_g, const float* __restrict__ ln1_b,
                     const float* __restrict__ ln2_g, const float* __restrict__ ln2_b,
                     const float* __restrict__ lnf_g, const float* __restrict__ lnf_b,
                     const float* __restrict__ ffn_w1, const float* __restrict__ ffn_b1,
                     const float* __restrict__ ffn_w2, const float* __restrict__ ffn_b2,
                     const float* __restrict__ head_w,
                     float* __restrict__ out, int B)
{
  // kv phase uses layout [t][row][12] (6120 floats, prefetch over-read <=6299);
  // logits phase [row][t][14] (7140 floats). Union: 7140.
  __shared__ __align__(16) float s_mem[RPB*BT*14];
  __shared__ int   s_idx[RPB*BT];
  __shared__ float s_te[42];
  __shared__ float s_pos[BT*3];
  __shared__ float s_wqf[18], s_wkf[18], s_wvf[18];   // ln1_g folded in
  __shared__ float s_qb[6], s_kb[6], s_vb[6];         // ln1_b folded in
  __shared__ float s_wo[36];
  __shared__ float s_w1f[12], s_fb1f[2];              // ln2_g/ln2_b folded in
  __shared__ float s_w2[12], s_fb2[6];
  __shared__ float s_hwf[18], s_yb[3];                // lnf_g/lnf_b folded in

  const int tid = threadIdx.x;
  const int b0  = blockIdx.x * RPB;

  // ---- stage params with LN-affine folds (all reads from GLOBAL: no ordering dep) ----
  if (tid < 42) s_te[tid] = tok_emb[tid];
  if (tid < 18) {
    const int r = tid / 6;
    s_wqf[tid] = wq[tid] * ln1_g[3+r];
    s_wkf[tid] = wk[tid] * ln1_g[3+r];
    s_wvf[tid] = wv[tid] * ln1_g[r];
    s_hwf[tid] = head_w[tid] * lnf_g[tid/3];
  }
  if (tid < 36) s_wo[tid] = wo[tid];
  if (tid < 12) { s_w1f[tid] = ffn_w1[tid] * ln2_g[tid>>1]; s_w2[tid] = ffn_w2[tid]; }
  if (tid < 6)  {
    s_qb[tid] = ln1_b[3]*wq[tid] + ln1_b[4]*wq[6+tid] + ln1_b[5]*wq[12+tid];
    s_kb[tid] = ln1_b[3]*wk[tid] + ln1_b[4]*wk[6+tid] + ln1_b[5]*wk[12+tid];
    s_vb[tid] = ln1_b[0]*wv[tid] + ln1_b[1]*wv[6+tid] + ln1_b[2]*wv[12+tid];
    s_fb2[tid] = ffn_b2[tid];
  }
  if (tid < 3) {
    float a = 0.f;
    #pragma unroll
    for (int c = 0; c < 6; ++c) a += lnf_b[c]*head_w[c*3+tid];
    s_yb[tid] = a;
  }
  if (tid < 2) {
    float a = ffn_b1[tid];
    #pragma unroll
    for (int d = 0; d < 6; ++d) a += ln2_b[d]*ffn_w1[d*2+tid];
    s_fb1f[tid] = a;
  }
  {
    int nr = B - b0; if (nr > RPB) nr = RPB;
    const int tot = nr * BT;
    for (int i = tid; i < tot; i += BLOCK) s_idx[i] = idx[b0*BT + i];
  }
  if (tid < BT) {
    int p = tid, f;
    if (p < 10) f = p;
    else if (p == 10) f = 11;
    else if (p < 21) f = p - 11;
    else if (p == 21) f = 12;
    else if (p < 33) { int z = p - 22; f = (z < 10) ? z : 10; }
    else f = 13;
    float e0, e1, e2;
    if (f < 10) {
      float amp = pos_params[0], ph = pos_params[1], sl = pos_params[2], of = pos_params[3];
      float ang = 0.62831853071795864769f * (float)f + ph;  // 2*pi*f/10 + phase
      e0 = amp * cosf(ang); e1 = amp * sinf(ang); e2 = sl * (float)f + of;
    } else if (f == 10) { e0 = z10_enc[0]; e1 = z10_enc[1]; e2 = z10_enc[2]; }
    else { int u = f - 11; e0 = special_enc[u*3]; e1 = special_enc[u*3+1]; e2 = special_enc[u*3+2]; }
    s_pos[tid*3+0] = e0; s_pos[tid*3+1] = e1; s_pos[tid*3+2] = e2;
  }
  __syncthreads();

  // transposed layout: waves hold a narrow j-band so causal trip counts are near-uniform
  const int row = tid % RPB;           // 0..14
  const int j   = tid / RPB;           // 0..16 (17 => inactive lane 255)
  const int b   = b0 + row;
  const bool active = (j < TPR) && (b < B);

  v2f qpA[3], qpB[3];                  // per-token q, packed over heads, scaled by QSCALE
  v2f x6[6];                           // residual x, packed over tokens (A,B)

  // ---- embed + ln1(folded) + qkv, token-packed; publish k,v to LDS [t][row] ----
  if (active) {
    const int tA = j, tB = j + TPR;
    const int vA = s_idx[row*BT + tA];
    const int vB = s_idx[row*BT + tB];
    #pragma unroll
    for (int c = 0; c < 3; ++c) {
      x6[c]   = (v2f){ s_te[vA*3+c],  s_te[vB*3+c]  };
      x6[3+c] = (v2f){ s_pos[tA*3+c], s_pos[tB*3+c] };
    }
    v2f h[6];
    ln6n(x6, h);
    v2f q6[6], k6[6], v6[6];
    #pragma unroll
    for (int c = 0; c < 6; ++c) {
      q6[c] = (v2f){s_qb[c], s_qb[c]} + h[3]*s_wqf[c] + h[4]*s_wqf[6+c] + h[5]*s_wqf[12+c];
      k6[c] = (v2f){s_kb[c], s_kb[c]} + h[3]*s_wkf[c] + h[4]*s_wkf[6+c] + h[5]*s_wkf[12+c];
      v6[c] = (v2f){s_vb[c], s_vb[c]} + h[0]*s_wvf[c] + h[1]*s_wvf[6+c] + h[2]*s_wvf[12+c];
    }
    #pragma unroll
    for (int d = 0; d < 3; ++d) {
      qpA[d] = (v2f){ q6[d].x, q6[3+d].x } * QSCALE;
      qpB[d] = (v2f){ q6[d].y, q6[3+d].y } * QSCALE;
    }
    v4f* pA = (v4f*)&s_mem[(tA*RPB + row)*12];
    pA[0] = (v4f){ k6[0].x, k6[3].x, k6[1].x, k6[4].x };
    pA[1] = (v4f){ k6[2].x, k6[5].x, v6[0].x, v6[3].x };
    pA[2] = (v4f){ v6[1].x, v6[4].x, v6[2].x, v6[5].x };
    v4f* pB = (v4f*)&s_mem[(tB*RPB + row)*12];
    pB[0] = (v4f){ k6[0].y, k6[3].y, k6[1].y, k6[4].y };
    pB[1] = (v4f){ k6[2].y, k6[5].y, v6[0].y, v6[3].y };
    pB[2] = (v4f){ v6[1].y, v6[4].y, v6[2].y, v6[5].y };
  }
  __syncthreads();

  // ---- causal attention: trip count IS the mask; rolling 1-deep kv prefetch ----
  v2f l0 = (v2f){0.f,0.f}, l1 = (v2f){0.f,0.f};
  v2f o0[3] = {(v2f){0.f,0.f},(v2f){0.f,0.f},(v2f){0.f,0.f}};
  v2f o1[3] = {(v2f){0.f,0.f},(v2f){0.f,0.f},(v2f){0.f,0.f}};
  if (active) {
    const float* kvbase = s_mem + row*12;
    v4f A  = ((const v4f*)kvbase)[0];
    v4f Bv = ((const v4f*)kvbase)[1];
    v4f C  = ((const v4f*)kvbase)[2];
    // k = 0..j : both tokens, no mask (wave runs jmax+1 iters: 5/9/13/17 per wave)
    for (int k = 0; k <= j; ++k) {
      const v4f Ac = A, Bc = Bv, Cc = C;
      const v4f* nxt = (const v4f*)(kvbase + (k+1)*(RPB*12));   // k+1<=17, in bounds
      A = nxt[0]; Bv = nxt[1]; C = nxt[2];
      v2f kA = (v2f){Ac.x, Ac.y}, kB = (v2f){Ac.z, Ac.w}, kC = (v2f){Bc.x, Bc.y};
      v2f vA = (v2f){Bc.z, Bc.w}, vB = (v2f){Cc.x, Cc.y}, vC = (v2f){Cc.z, Cc.w};
      v2f s0 = qpA[0]*kA + qpA[1]*kB + qpA[2]*kC;
      v2f p0 = (v2f){EXP2(s0.x), EXP2(s0.y)};
      l0 += p0; o0[0] += p0*vA; o0[1] += p0*vB; o0[2] += p0*vC;
      v2f s1 = qpB[0]*kA + qpB[1]*kB + qpB[2]*kC;
      v2f p1 = (v2f){EXP2(s1.x), EXP2(s1.y)};
      l1 += p1; o1[0] += p1*vA; o1[1] += p1*vB; o1[2] += p1*vC;
    }
    // k = j+1..j+17 : token B only, exactly 17 iters for every lane (uniform trip).
    // A/Bv/C already hold kv[j+1] from the last prefetch above.
    #pragma unroll 4
    for (int i = 1; i <= TPR; ++i) {
      const int k = j + i;
      const v4f Ac = A, Bc = Bv, Cc = C;
      const v4f* nxt = (const v4f*)(kvbase + (k+1)*(RPB*12));   // max idx 6299 < 7140: in s_mem, value unused
      A = nxt[0]; Bv = nxt[1]; C = nxt[2];
      v2f kA = (v2f){Ac.x, Ac.y}, kB = (v2f){Ac.z, Ac.w}, kC = (v2f){Bc.x, Bc.y};
      v2f vA = (v2f){Bc.z, Bc.w}, vB = (v2f){Cc.x, Cc.y}, vC = (v2f){Cc.z, Cc.w};
      v2f s1 = qpB[0]*kA + qpB[1]*kB + qpB[2]*kC;
      v2f p1 = (v2f){EXP2(s1.x), EXP2(s1.y)};
      l1 += p1; o1[0] += p1*vA; o1[1] += p1*vB; o1[2] += p1*vC;
    }
  }
  __syncthreads();   // all kv reads done; s_mem is free for logits

  // ---- epilogue, token-packed: o/l, wo, residual, ln2(folded), FFN(exact gelu),
  //      lnf(folded), head -> logits staged to LDS for the coalesced store ----
  if (active) {
    const float rA0 = __builtin_amdgcn_rcpf(l0.x);
    const float rA1 = __builtin_amdgcn_rcpf(l0.y);
    const float rB0 = __builtin_amdgcn_rcpf(l1.x);
    const float rB1 = __builtin_amdgcn_rcpf(l1.y);
    v2f a6[6];
    a6[0] = (v2f){ o0[0].x*rA0, o1[0].x*rB0 };
    a6[1] = (v2f){ o0[1].x*rA0, o1[1].x*rB0 };
    a6[2] = (v2f){ o0[2].x*rA0, o1[2].x*rB0 };
    a6[3] = (v2f){ o0[0].y*rA1, o1[0].y*rB1 };
    a6[4] = (v2f){ o0[1].y*rA1, o1[1].y*rB1 };
    a6[5] = (v2f){ o0[2].y*rA1, o1[2].y*rB1 };
    v2f xn[6];
    #pragma unroll
    for (int c = 0; c < 6; ++c) {
      xn[c] = x6[c]
            + a6[0]*s_wo[c]    + a6[1]*s_wo[6+c]  + a6[2]*s_wo[12+c]
            + a6[3]*s_wo[18+c] + a6[4]*s_wo[24+c] + a6[5]*s_wo[30+c];
    }
    v2f t2[6];
    ln6n(xn, t2);
    v2f a0 = (v2f){s_fb1f[0], s_fb1f[0]};
    v2f a1 = (v2f){s_fb1f[1], s_fb1f[1]};
    #pragma unroll
    for (int d = 0; d < 6; ++d) { a0 += t2[d]*s_w1f[d*2]; a1 += t2[d]*s_w1f[d*2+1]; }
    const float KIS2 = 0.70710678118654752440f;
    v2f g0 = (v2f){ 0.5f*a0.x*(1.0f + erff(a0.x*KIS2)),
                    0.5f*a0.y*(1.0f + erff(a0.y*KIS2)) };
    v2f g1 = (v2f){ 0.5f*a1.x*(1.0f + erff(a1.x*KIS2)),
                    0.5f*a1.y*(1.0f + erff(a1.y*KIS2)) };
    #pragma unroll
    for (int c = 0; c < 6; ++c) xn[c] += g0*s_w2[c] + g1*s_w2[6+c] + s_fb2[c];
    v2f tf[6];
    ln6n(xn, tf);
    v2f y0 = (v2f){s_yb[0], s_yb[0]};
    v2f y1 = (v2f){s_yb[1], s_yb[1]};
    v2f y2 = (v2f){s_yb[2], s_yb[2]};
    #pragma unroll
    for (int c = 0; c < 6; ++c) {
      y0 += tf[c]*s_hwf[c*3+0]; y1 += tf[c]*s_hwf[c*3+1]; y2 += tf[c]*s_hwf[c*3+2];
    }
    // stage logits to LDS [row][t][14] as v2f pairs for the coalesced store
    v2f* lpA = (v2f*)&s_mem[(row*BT + j      )*14];
    v2f* lpB = (v2f*)&s_mem[(row*BT + j + TPR)*14];
    #pragma unroll
    for (int u = 0; u < 7; ++u) {
      const int c0 = 2*u, c1 = 2*u+1;
      v2f lg0 = y0*s_te[c0*3+0] + y1*s_te[c0*3+1] + y2*s_te[c0*3+2];
      v2f lg1 = y0*s_te[c1*3+0] + y1*s_te[c1*3+1] + y2*s_te[c1*3+2];
      lpA[u] = (v2f){ lg0.x, lg1.x };
      lpB[u] = (v2f){ lg0.y, lg1.y };
    }
  }
  __syncthreads();

  // ---- coalesced nontemporal v4f store of the block's contiguous output ----
  {
    int nrows = B - b0; if (nrows > RPB) nrows = RPB;
    if (nrows > 0) {
      const int n4 = nrows * (BT*14/4);   // 476/4 = 119 vec4 per row
      v4f* dst = reinterpret_cast<v4f*>(out + (size_t)b0 * (BT*14));
      const v4f* src = reinterpret_cast<const v4f*>(s_mem);
      for (int i = tid; i < n4; i += BLOCK)
        __builtin_nontemporal_store(src[i], dst + i);
    }
  }
}

extern "C" void kernel_launch(void* const* d_in, const int* in_sizes, int n_in,
                              void* d_out, int out_size, void* d_ws, size_t ws_size,
                              hipStream_t stream) {
  const int B = in_sizes[0] / BT;                 // 32768
  const int grid = (B + RPB - 1) / RPB;           // 2185
  addtrans_kernel<<<grid, BLOCK, 0, stream>>>(
      (const int*)d_in[0],   (const float*)d_in[1], (const float*)d_in[2],
      (const float*)d_in[3], (const float*)d_in[4], (const float*)d_in[5],
      (const float*)d_in[6], (const float*)d_in[7], (const float*)d_in[8],
      (const float*)d_in[9], (const float*)d_in[10], (const float*)d_in[11],
      (const float*)d_in[12], (const float*)d_in[13], (const float*)d_in[14],
      (const float*)d_in[15], (const float*)d_in[16], (const float*)d_in[17],
      (const float*)d_in[18], (const float*)d_in[19],
      (float*)d_out, B);
}

// Round 4
// 133.330 us; speedup vs baseline: 1.0538x; 1.0040x over previous
//
#include <hip/hip_runtime.h>
#include <math.h>

#define BT    34   // sequence length
#define TPR   17   // j index range: thread owns tokens j and j+17
#define RPB   15   // rows per block (15*17 = 255 active threads of 256)
#define BLOCK 256

typedef float v2f __attribute__((ext_vector_type(2)));
typedef float v4f __attribute__((ext_vector_type(4)));

// log2(e)/sqrt(3): folds the 1/sqrt(hd) scale AND the exp->exp2 conversion into q.
#define QSCALE 0.83294037332470f

#if __has_builtin(__builtin_amdgcn_exp2f)
#define EXP2(x) __builtin_amdgcn_exp2f(x)
#else
#define EXP2(x) exp2f(x)
#endif

// token-packed normalize-only layernorm (affine folded into downstream weights)
__device__ __forceinline__ void ln6n(const v2f* x, v2f* o) {
  v2f mu = (x[0]+x[1]+x[2]+x[3]+x[4]+x[5]) * (1.0f/6.0f);
  v2f v = (v2f){0.f, 0.f};
  #pragma unroll
  for (int c = 0; c < 6; ++c) { v2f d = x[c]-mu; v += d*d; }
  v2f inv = (v2f){ rsqrtf(v.x*(1.0f/6.0f) + 1e-5f),
                   rsqrtf(v.y*(1.0f/6.0f) + 1e-5f) };
  #pragma unroll
  for (int c = 0; c < 6; ++c) o[c] = (x[c]-mu)*inv;
}

__global__ __launch_bounds__(BLOCK, 5)
void addtrans_kernel(const int* __restrict__ idx,
                     const float* __restrict__ tok_emb,
                     const float* __restrict__ pos_params,
                     const float* __restrict__ z10_enc,
                     const float* __restrict__ special_enc,
                     const float* __restrict__ wq,
                     const float* __restrict__ wk,
                     const float* __restrict__ wv,
                     const float* __restrict__ wo,
                     const float* __restrict__ ln1_g, const float* __restrict__ ln1_b,
                     const float* __restrict__ ln2_g, const float* __restrict__ ln2_b,
                     const float* __restrict__ lnf_g, const float* __restrict__ lnf_b,
                     const float* __restrict__ ffn_w1, const float* __restrict__ ffn_b1,
                     const float* __restrict__ ffn_w2, const float* __restrict__ ffn_b2,
                     const float* __restrict__ head_w,
                     float* __restrict__ out, int B)
{
  // kv phase uses layout [t][row][12] (6120 floats); logits phase [row][t][14] (7140).
  __shared__ __align__(16) float s_mem[RPB*BT*14];
  __shared__ int   s_idx[RPB*BT];
  __shared__ float s_te[42];
  __shared__ float s_pos[BT*3];
  __shared__ float s_wqf[18], s_wkf[18], s_wvf[18];   // ln1_g folded in
  __shared__ float s_qb[6], s_kb[6], s_vb[6];         // ln1_b folded in
  __shared__ float s_wo[36];
  __shared__ float s_w1f[12], s_fb1f[2];              // ln2_g/ln2_b folded in
  __shared__ float s_w2[12], s_fb2[6];
  __shared__ float s_hwf[18], s_yb[3];                // lnf_g/lnf_b folded in

  const int tid = threadIdx.x;
  const int b0  = blockIdx.x * RPB;

  // ---- stage params with LN-affine folds (all reads from GLOBAL: no ordering dep) ----
  if (tid < 42) s_te[tid] = tok_emb[tid];
  if (tid < 18) {
    const int r = tid / 6;
    s_wqf[tid] = wq[tid] * ln1_g[3+r];
    s_wkf[tid] = wk[tid] * ln1_g[3+r];
    s_wvf[tid] = wv[tid] * ln1_g[r];
    s_hwf[tid] = head_w[tid] * lnf_g[tid/3];
  }
  if (tid < 36) s_wo[tid] = wo[tid];
  if (tid < 12) { s_w1f[tid] = ffn_w1[tid] * ln2_g[tid>>1]; s_w2[tid] = ffn_w2[tid]; }
  if (tid < 6)  {
    s_qb[tid] = ln1_b[3]*wq[tid] + ln1_b[4]*wq[6+tid] + ln1_b[5]*wq[12+tid];
    s_kb[tid] = ln1_b[3]*wk[tid] + ln1_b[4]*wk[6+tid] + ln1_b[5]*wk[12+tid];
    s_vb[tid] = ln1_b[0]*wv[tid] + ln1_b[1]*wv[6+tid] + ln1_b[2]*wv[12+tid];
    s_fb2[tid] = ffn_b2[tid];
  }
  if (tid < 3) {
    float a = 0.f;
    #pragma unroll
    for (int c = 0; c < 6; ++c) a += lnf_b[c]*head_w[c*3+tid];
    s_yb[tid] = a;
  }
  if (tid < 2) {
    float a = ffn_b1[tid];
    #pragma unroll
    for (int d = 0; d < 6; ++d) a += ln2_b[d]*ffn_w1[d*2+tid];
    s_fb1f[tid] = a;
  }
  {
    int nr = B - b0; if (nr > RPB) nr = RPB;
    const int tot = nr * BT;
    for (int i = tid; i < tot; i += BLOCK) s_idx[i] = idx[b0*BT + i];
  }
  if (tid < BT) {
    int p = tid, f;
    if (p < 10) f = p;
    else if (p == 10) f = 11;
    else if (p < 21) f = p - 11;
    else if (p == 21) f = 12;
    else if (p < 33) { int z = p - 22; f = (z < 10) ? z : 10; }
    else f = 13;
    float e0, e1, e2;
    if (f < 10) {
      float amp = pos_params[0], ph = pos_params[1], sl = pos_params[2], of = pos_params[3];
      float ang = 0.62831853071795864769f * (float)f + ph;  // 2*pi*f/10 + phase
      e0 = amp * cosf(ang); e1 = amp * sinf(ang); e2 = sl * (float)f + of;
    } else if (f == 10) { e0 = z10_enc[0]; e1 = z10_enc[1]; e2 = z10_enc[2]; }
    else { int u = f - 11; e0 = special_enc[u*3]; e1 = special_enc[u*3+1]; e2 = special_enc[u*3+2]; }
    s_pos[tid*3+0] = e0; s_pos[tid*3+1] = e1; s_pos[tid*3+2] = e2;
  }
  __syncthreads();

  // transposed layout: waves hold a narrow j-band so causal trip counts are near-uniform
  const int row = tid % RPB;           // 0..14
  const int j   = tid / RPB;           // 0..16 (17 => inactive lane 255)
  const int b   = b0 + row;
  const bool active = (j < TPR) && (b < B);

  v2f qpA[3], qpB[3];                  // per-token q, packed over heads, scaled by QSCALE
  v2f x6[6];                           // residual x, packed over tokens (A,B)

  // ---- embed + ln1(folded) + qkv, token-packed; publish k,v to LDS [t][row] ----
  if (active) {
    const int tA = j, tB = j + TPR;
    const int vA = s_idx[row*BT + tA];
    const int vB = s_idx[row*BT + tB];
    #pragma unroll
    for (int c = 0; c < 3; ++c) {
      x6[c]   = (v2f){ s_te[vA*3+c],  s_te[vB*3+c]  };
      x6[3+c] = (v2f){ s_pos[tA*3+c], s_pos[tB*3+c] };
    }
    v2f h[6];
    ln6n(x6, h);
    v2f q6[6], k6[6], v6[6];
    #pragma unroll
    for (int c = 0; c < 6; ++c) {
      q6[c] = (v2f){s_qb[c], s_qb[c]} + h[3]*s_wqf[c] + h[4]*s_wqf[6+c] + h[5]*s_wqf[12+c];
      k6[c] = (v2f){s_kb[c], s_kb[c]} + h[3]*s_wkf[c] + h[4]*s_wkf[6+c] + h[5]*s_wkf[12+c];
      v6[c] = (v2f){s_vb[c], s_vb[c]} + h[0]*s_wvf[c] + h[1]*s_wvf[6+c] + h[2]*s_wvf[12+c];
    }
    #pragma unroll
    for (int d = 0; d < 3; ++d) {
      qpA[d] = (v2f){ q6[d].x, q6[3+d].x } * QSCALE;
      qpB[d] = (v2f){ q6[d].y, q6[3+d].y } * QSCALE;
    }
    v4f* pA = (v4f*)&s_mem[(tA*RPB + row)*12];
    pA[0] = (v4f){ k6[0].x, k6[3].x, k6[1].x, k6[4].x };
    pA[1] = (v4f){ k6[2].x, k6[5].x, v6[0].x, v6[3].x };
    pA[2] = (v4f){ v6[1].x, v6[4].x, v6[2].x, v6[5].x };
    v4f* pB = (v4f*)&s_mem[(tB*RPB + row)*12];
    pB[0] = (v4f){ k6[0].y, k6[3].y, k6[1].y, k6[4].y };
    pB[1] = (v4f){ k6[2].y, k6[5].y, v6[0].y, v6[3].y };
    pB[2] = (v4f){ v6[1].y, v6[4].y, v6[2].y, v6[5].y };
  }
  __syncthreads();

  // ---- causal attention: trip count IS the mask ----
  v2f l0 = (v2f){0.f,0.f}, l1 = (v2f){0.f,0.f};
  v2f o0[3] = {(v2f){0.f,0.f},(v2f){0.f,0.f},(v2f){0.f,0.f}};
  v2f o1[3] = {(v2f){0.f,0.f},(v2f){0.f,0.f},(v2f){0.f,0.f}};
  if (active) {
    const float* kvbase = s_mem + row*12;

    // ---- loop1: k = 0..j, both tokens. 2-deep ping-pong prefetch (two static
    //      register sets; manual unroll-2 so no runtime-indexed regs, no
    //      loop-carried single-register chain). Max load index j+3 <= 19: valid data.
    v4f A0 = ((const v4f*)(kvbase))[0];
    v4f B0 = ((const v4f*)(kvbase))[1];
    v4f C0 = ((const v4f*)(kvbase))[2];
    v4f A1 = ((const v4f*)(kvbase + RPB*12))[0];
    v4f B1 = ((const v4f*)(kvbase + RPB*12))[1];
    v4f C1 = ((const v4f*)(kvbase + RPB*12))[2];
    for (int k = 0; k <= j; k += 2) {
      {
        v2f kA = (v2f){A0.x, A0.y}, kB = (v2f){A0.z, A0.w}, kC = (v2f){B0.x, B0.y};
        v2f vA = (v2f){B0.z, B0.w}, vB = (v2f){C0.x, C0.y}, vC = (v2f){C0.z, C0.w};
        v2f s0 = qpA[0]*kA + qpA[1]*kB + qpA[2]*kC;
        v2f p0 = (v2f){EXP2(s0.x), EXP2(s0.y)};
        l0 += p0; o0[0] += p0*vA; o0[1] += p0*vB; o0[2] += p0*vC;
        v2f s1 = qpB[0]*kA + qpB[1]*kB + qpB[2]*kC;
        v2f p1 = (v2f){EXP2(s1.x), EXP2(s1.y)};
        l1 += p1; o1[0] += p1*vA; o1[1] += p1*vB; o1[2] += p1*vC;
        const v4f* nx = (const v4f*)(kvbase + (k+2)*(RPB*12));   // k+2 <= 18: valid
        A0 = nx[0]; B0 = nx[1]; C0 = nx[2];
      }
      if (k + 1 <= j) {
        v2f kA = (v2f){A1.x, A1.y}, kB = (v2f){A1.z, A1.w}, kC = (v2f){B1.x, B1.y};
        v2f vA = (v2f){B1.z, B1.w}, vB = (v2f){C1.x, C1.y}, vC = (v2f){C1.z, C1.w};
        v2f s0 = qpA[0]*kA + qpA[1]*kB + qpA[2]*kC;
        v2f p0 = (v2f){EXP2(s0.x), EXP2(s0.y)};
        l0 += p0; o0[0] += p0*vA; o0[1] += p0*vB; o0[2] += p0*vC;
        v2f s1 = qpB[0]*kA + qpB[1]*kB + qpB[2]*kC;
        v2f p1 = (v2f){EXP2(s1.x), EXP2(s1.y)};
        l1 += p1; o1[0] += p1*vA; o1[1] += p1*vB; o1[2] += p1*vC;
        const v4f* nx = (const v4f*)(kvbase + (k+3)*(RPB*12));   // k+3 <= 19: valid
        A1 = nx[0]; B1 = nx[1]; C1 = nx[2];
      }
    }

    // ---- loop2: k = j+1..j+17, token B only. Uniform 17 trips -> FULL unroll,
    //      direct indexing, no loop-carried register chain: the compiler is free
    //      to hoist/pipeline the 51 independent ds_read_b128 with counted lgkmcnt.
    #pragma unroll
    for (int i = 1; i <= TPR; ++i) {
      const v4f* p = (const v4f*)(kvbase + (j+i)*(RPB*12));      // max index 33: exact
      v4f Ac = p[0], Bc = p[1], Cc = p[2];
      v2f kA = (v2f){Ac.x, Ac.y}, kB = (v2f){Ac.z, Ac.w}, kC = (v2f){Bc.x, Bc.y};
      v2f vA = (v2f){Bc.z, Bc.w}, vB = (v2f){Cc.x, Cc.y}, vC = (v2f){Cc.z, Cc.w};
      v2f s1 = qpB[0]*kA + qpB[1]*kB + qpB[2]*kC;
      v2f p1 = (v2f){EXP2(s1.x), EXP2(s1.y)};
      l1 += p1; o1[0] += p1*vA; o1[1] += p1*vB; o1[2] += p1*vC;
    }
  }
  __syncthreads();   // all kv reads done; s_mem is free for logits

  // ---- epilogue, token-packed: o/l, wo, residual, ln2(folded), FFN(exact gelu),
  //      lnf(folded), head -> logits staged to LDS for the coalesced store ----
  if (active) {
    const float rA0 = __builtin_amdgcn_rcpf(l0.x);
    const float rA1 = __builtin_amdgcn_rcpf(l0.y);
    const float rB0 = __builtin_amdgcn_rcpf(l1.x);
    const float rB1 = __builtin_amdgcn_rcpf(l1.y);
    v2f a6[6];
    a6[0] = (v2f){ o0[0].x*rA0, o1[0].x*rB0 };
    a6[1] = (v2f){ o0[1].x*rA0, o1[1].x*rB0 };
    a6[2] = (v2f){ o0[2].x*rA0, o1[2].x*rB0 };
    a6[3] = (v2f){ o0[0].y*rA1, o1[0].y*rB1 };
    a6[4] = (v2f){ o0[1].y*rA1, o1[1].y*rB1 };
    a6[5] = (v2f){ o0[2].y*rA1, o1[2].y*rB1 };
    v2f xn[6];
    #pragma unroll
    for (int c = 0; c < 6; ++c) {
      xn[c] = x6[c]
            + a6[0]*s_wo[c]    + a6[1]*s_wo[6+c]  + a6[2]*s_wo[12+c]
            + a6[3]*s_wo[18+c] + a6[4]*s_wo[24+c] + a6[5]*s_wo[30+c];
    }
    v2f t2[6];
    ln6n(xn, t2);
    v2f a0 = (v2f){s_fb1f[0], s_fb1f[0]};
    v2f a1 = (v2f){s_fb1f[1], s_fb1f[1]};
    #pragma unroll
    for (int d = 0; d < 6; ++d) { a0 += t2[d]*s_w1f[d*2]; a1 += t2[d]*s_w1f[d*2+1]; }
    const float KIS2 = 0.70710678118654752440f;
    v2f g0 = (v2f){ 0.5f*a0.x*(1.0f + erff(a0.x*KIS2)),
                    0.5f*a0.y*(1.0f + erff(a0.y*KIS2)) };
    v2f g1 = (v2f){ 0.5f*a1.x*(1.0f + erff(a1.x*KIS2)),
                    0.5f*a1.y*(1.0f + erff(a1.y*KIS2)) };
    #pragma unroll
    for (int c = 0; c < 6; ++c) xn[c] += g0*s_w2[c] + g1*s_w2[6+c] + s_fb2[c];
    v2f tf[6];
    ln6n(xn, tf);
    v2f y0 = (v2f){s_yb[0], s_yb[0]};
    v2f y1 = (v2f){s_yb[1], s_yb[1]};
    v2f y2 = (v2f){s_yb[2], s_yb[2]};
    #pragma unroll
    for (int c = 0; c < 6; ++c) {
      y0 += tf[c]*s_hwf[c*3+0]; y1 += tf[c]*s_hwf[c*3+1]; y2 += tf[c]*s_hwf[c*3+2];
    }
    // stage logits to LDS [row][t][14] as v2f pairs for the coalesced store
    v2f* lpA = (v2f*)&s_mem[(row*BT + j      )*14];
    v2f* lpB = (v2f*)&s_mem[(row*BT + j + TPR)*14];
    #pragma unroll
    for (int u = 0; u < 7; ++u) {
      const int c0 = 2*u, c1 = 2*u+1;
      v2f lg0 = y0*s_te[c0*3+0] + y1*s_te[c0*3+1] + y2*s_te[c0*3+2];
      v2f lg1 = y0*s_te[c1*3+0] + y1*s_te[c1*3+1] + y2*s_te[c1*3+2];
      lpA[u] = (v2f){ lg0.x, lg1.x };
      lpB[u] = (v2f){ lg0.y, lg1.y };
    }
  }
  __syncthreads();

  // ---- coalesced nontemporal v4f store of the block's contiguous output ----
  {
    int nrows = B - b0; if (nrows > RPB) nrows = RPB;
    if (nrows > 0) {
      const int n4 = nrows * (BT*14/4);   // 476/4 = 119 vec4 per row
      v4f* dst = reinterpret_cast<v4f*>(out + (size_t)b0 * (BT*14));
      const v4f* src = reinterpret_cast<const v4f*>(s_mem);
      for (int i = tid; i < n4; i += BLOCK)
        __builtin_nontemporal_store(src[i], dst + i);
    }
  }
}

extern "C" void kernel_launch(void* const* d_in, const int* in_sizes, int n_in,
                              void* d_out, int out_size, void* d_ws, size_t ws_size,
                              hipStream_t stream) {
  const int B = in_sizes[0] / BT;                 // 32768
  const int grid = (B + RPB - 1) / RPB;           // 2185
  addtrans_kernel<<<grid, BLOCK, 0, stream>>>(
      (const int*)d_in[0],   (const float*)d_in[1], (const float*)d_in[2],
      (const float*)d_in[3], (const float*)d_in[4], (const float*)d_in[5],
      (const float*)d_in[6], (const float*)d_in[7], (const float*)d_in[8],
      (const float*)d_in[9], (const float*)d_in[10], (const float*)d_in[11],
      (const float*)d_in[12], (const float*)d_in[13], (const float*)d_in[14],
      (const float*)d_in[15], (const float*)d_in[16], (const float*)d_in[17],
      (const float*)d_in[18], (const float*)d_in[19],
      (float*)d_out, B);
}